// Round 8
// baseline (7813.483 us; speedup 1.0000x reference)
//
#include <hip/hip_runtime.h>

#define NBATCH 16
#define NPTS   1024
#define NDIM   1024
#define EPSI   1e-3f
#define QSCALE 127.5f
#define SPIN_TIMEOUT_TICKS (1ull << 28)   // s_memrealtime ticks; >>1000x any real wait

typedef __attribute__((ext_vector_type(8))) short short8;
typedef __attribute__((ext_vector_type(4))) float f32x4;
typedef __attribute__((ext_vector_type(4))) unsigned uint32x4;

__device__ __forceinline__ unsigned short f2bf(float f) {
  union { float f; unsigned u; } v; v.f = f;
  unsigned r = v.u + 0x7fffu + ((v.u >> 16) & 1u);
  return (unsigned short)(r >> 16);
}

// device-coherent scalar access (per-access sc bits; NO cache-wide fences)
__device__ __forceinline__ void st_agent(float* p, float v) {
  __hip_atomic_store(p, v, __ATOMIC_RELAXED, __HIP_MEMORY_SCOPE_AGENT);
}
__device__ __forceinline__ unsigned long long ld_agent64(const unsigned long long* p) {
  return __hip_atomic_load(p, __ATOMIC_RELAXED, __HIP_MEMORY_SCOPE_AGENT);
}

// ---------------- normalize: fp32 [B,N,D] -> unit rows, bf16 ----------------
__global__ __launch_bounds__(256) void norm_kernel(const float* __restrict__ x,
                                                   const float* __restrict__ y,
                                                   unsigned short* __restrict__ xf,
                                                   unsigned short* __restrict__ yf) {
  int row = blockIdx.x;
  const float* src; unsigned short* dst;
  if (row < NBATCH * NPTS) { src = x; dst = xf; }
  else { row -= NBATCH * NPTS; src = y; dst = yf; }
  src += (size_t)row * NDIM; dst += (size_t)row * NDIM;
  const int t = threadIdx.x;
  float4 val = ((const float4*)src)[t];
  float ss = val.x*val.x + val.y*val.y + val.z*val.z + val.w*val.w;
  #pragma unroll
  for (int o = 32; o; o >>= 1) ss += __shfl_xor(ss, o, 64);
  __shared__ float wsum[4];
  if ((t & 63) == 0) wsum[t >> 6] = ss;
  __syncthreads();
  float tot = wsum[0] + wsum[1] + wsum[2] + wsum[3];
  float inv = 1.0f / fmaxf(sqrtf(tot), 1e-12f);
  ushort4 o4;
  o4.x = f2bf(val.x * inv); o4.y = f2bf(val.y * inv);
  o4.z = f2bf(val.z * inv); o4.w = f2bf(val.w * inv);
  ((ushort4*)dst)[t] = o4;
}

// ------- batched bf16 GEMM: writes BOTH Cq = q8(1 - A B^T) and its transpose -------
#define GLD_LDS16(g, l) __builtin_amdgcn_global_load_lds( \
    (const __attribute__((address_space(1))) unsigned int*)(g), \
    (__attribute__((address_space(3))) unsigned int*)(l), 16, 0, 0)

__device__ __forceinline__ unsigned char q8(float cv) {
  float t = cv * QSCALE + 0.5f;
  t = fminf(fmaxf(t, 0.f), 255.f);
  return (unsigned char)(int)t;
}

__global__ __launch_bounds__(256) void gemm_cost(const unsigned short* __restrict__ A,
                                                 const unsigned short* __restrict__ B,
                                                 unsigned char* __restrict__ Cq,
                                                 unsigned char* __restrict__ CTq,
                                                 unsigned* __restrict__ cmax_bits) {
  const int b = blockIdx.z;
  const int bm = blockIdx.y * 128, bn = blockIdx.x * 128;
  const int t = threadIdx.x, lane = t & 63, wv = t >> 6;
  const int wm = (wv & 1) * 64, wn = (wv >> 1) * 64;
  __shared__ unsigned short As[128 * 32];
  __shared__ unsigned short Bs[128 * 32];
  f32x4 acc[4][4];
  #pragma unroll
  for (int i = 0; i < 4; ++i)
    #pragma unroll
    for (int j = 0; j < 4; ++j) acc[i][j] = (f32x4){0.f, 0.f, 0.f, 0.f};

  const unsigned short* gA = A + (size_t)b*NPTS*NDIM + (size_t)(bm + (t >> 2))*NDIM + (t & 3)*8;
  const unsigned short* gB = B + (size_t)b*NPTS*NDIM + (size_t)(bn + (t >> 2))*NDIM + (t & 3)*8;
  const int ar = lane & 15, ak = (lane >> 4) * 8;

  for (int k0 = 0; k0 < NDIM; k0 += 32) {
    GLD_LDS16(gA + k0,             As + t*8);
    GLD_LDS16(gA + 64*NDIM + k0,   As + 2048 + t*8);
    GLD_LDS16(gB + k0,             Bs + t*8);
    GLD_LDS16(gB + 64*NDIM + k0,   Bs + 2048 + t*8);
    __syncthreads();
    short8 af[4], bq[4];
    #pragma unroll
    for (int i = 0; i < 4; ++i) af[i] = *(const short8*)(As + (wm + i*16 + ar)*32 + ak);
    #pragma unroll
    for (int j = 0; j < 4; ++j) bq[j] = *(const short8*)(Bs + (wn + j*16 + ar)*32 + ak);
    #pragma unroll
    for (int i = 0; i < 4; ++i)
      #pragma unroll
      for (int j = 0; j < 4; ++j)
        acc[i][j] = __builtin_amdgcn_mfma_f32_16x16x32_bf16(af[i], bq[j], acc[i][j], 0, 0, 0);
    __syncthreads();
  }

  float mx = 0.f;
  const int cr = (lane >> 4) * 4, cc = lane & 15;
  unsigned char* Cb = Cq  + (size_t)b * NPTS * NPTS;
  unsigned char* Tb = CTq + (size_t)b * NPTS * NPTS;
  #pragma unroll
  for (int i = 0; i < 4; ++i) {
    #pragma unroll
    for (int j = 0; j < 4; ++j) {
      const int row0 = bm + wm + i*16 + cr;
      const int col  = bn + wn + j*16 + cc;
      #pragma unroll
      for (int r = 0; r < 4; ++r) {
        float cv = 1.0f - acc[i][j][r];
        mx = fmaxf(mx, cv);
        unsigned char qv = q8(cv);
        Cb[(size_t)(row0 + r) * NPTS + col] = qv;
        Tb[(size_t)col * NPTS + row0 + r]   = qv;
      }
    }
  }
  #pragma unroll
  for (int o = 32; o; o >>= 1) mx = fmaxf(mx, __shfl_xor(mx, o, 64));
  if (lane == 0) atomicMax(cmax_bits, __float_as_uint(mx));
}

// ---- persistent Sinkhorn: per-producer FLAG sync + dual-batch pipeline ----
// 128 WGs x 512 thr. WG (p,s) runs slice s (rows/v-outputs [64s,64s+64)) of TWO
// independent batches b0=p, b1=p+8. Per iteration:
//   compute0 (u0, partials0, plane store) -> flag0[s]=it+1   (release store, OWN 64B line)
//   compute1 (same for b1)                -> flag1[s]=it+1   (~3.5us hides flag0 latency)
//   wait0: wave0 lanes 0..15 poll the 16 flag lines in ONE parallel load + __all
//   consume0: R6-proven redundant 16-plane sum -> v#(it+1) -> permuted gst0
//   wait1 / consume1.
// Rationale (R6 vs R7 decomposition): work ~5.6us/iter constant; each COUNTER
// barrier ~5.1us == 16 serialized same-line RMWs. Flags-on-own-lines kill the
// RMW serialization; pairing hides the store->observe latency behind compute.
// Plane parity double-buffer + causality (write(it+1) only after all consumed(it))
// unchanged from R6. Distance at it==99 (s==0 WG), invc2 applied at the end.

__device__ __forceinline__ float dot16(uint32x4 q, f32x4 g0, f32x4 g1, f32x4 g2, f32x4 g3) {
  float a = 0.f;
  a += (float)( q.x        & 0xffu) * g0.x;   // v_cvt_f32_ubyte0
  a += (float)((q.x >>  8) & 0xffu) * g0.y;
  a += (float)((q.x >> 16) & 0xffu) * g0.z;
  a += (float)( q.x >> 24         ) * g0.w;
  a += (float)( q.y        & 0xffu) * g1.x;
  a += (float)((q.y >>  8) & 0xffu) * g1.y;
  a += (float)((q.y >> 16) & 0xffu) * g1.z;
  a += (float)( q.y >> 24         ) * g1.w;
  a += (float)( q.z        & 0xffu) * g2.x;
  a += (float)((q.z >>  8) & 0xffu) * g2.y;
  a += (float)((q.z >> 16) & 0xffu) * g2.z;
  a += (float)( q.z >> 24         ) * g2.w;
  a += (float)( q.w        & 0xffu) * g3.x;
  a += (float)((q.w >>  8) & 0xffu) * g3.y;
  a += (float)((q.w >> 16) & 0xffu) * g3.z;
  a += (float)( q.w >> 24         ) * g3.w;
  return a;
}

// wave 0 polls 16 per-producer flag lines (stride 16 uints = 64B) until all >= tag
__device__ __forceinline__ void wait_flags(const unsigned* flagb, unsigned tag,
                                           int tid, int lane, int* s_tmo) {
  if (tid < 64) {
    if (!*s_tmo) {
      int polls = 0; unsigned long long t0 = 0;
      for (;;) {
        unsigned val = tag;
        if (lane < 16)
          val = __hip_atomic_load(flagb + lane * 16, __ATOMIC_RELAXED, __HIP_MEMORY_SCOPE_AGENT);
        if (__all(val >= tag)) break;
        __builtin_amdgcn_s_sleep(1);
        if ((++polls & 63) == 0) {
          if (!t0) t0 = __builtin_amdgcn_s_memrealtime();
          else if (__builtin_amdgcn_s_memrealtime() - t0 > SPIN_TIMEOUT_TICKS) { *s_tmo = 1; break; }
        }
      }
    }
    asm volatile("" ::: "memory");
  }
  __syncthreads();
}

// compute phase: u for 8 rows -> LDS hop -> partials for all m -> plane store -> flag
#define COMPUTE_PHASE(GST, MC, MD0, MD1, BIDX, FLAGB)                          \
  {                                                                            \
    const f32x4 g0 = *(const f32x4*)&GST[      lane * 4];                      \
    const f32x4 g1 = *(const f32x4*)&GST[256 + lane * 4];                      \
    const f32x4 g2 = *(const f32x4*)&GST[512 + lane * 4];                      \
    const f32x4 g3 = *(const f32x4*)&GST[768 + lane * 4];                      \
    float myu = 0.f;                                                           \
    _Pragma("unroll")                                                          \
    for (int q = 0; q < 8; ++q) {                                              \
      float acc = dot16(MC[q], g0, g1, g2, g3);                                \
      _Pragma("unroll")                                                        \
      for (int o = 32; o; o >>= 1) acc += __shfl_xor(acc, o, 64);              \
      const float val = 1.0f / (acc * invc2 + EPSI);                           \
      myu = (lane == q) ? val : myu;                                           \
    }                                                                          \
    if (lane < 8) lds_u[w * 8 + lane] = myu;                                   \
  }                                                                            \
  __syncthreads();                                                             \
  {                                                                            \
    float p0 = 0.f, p1 = 0.f;                                                  \
    _Pragma("unroll")                                                          \
    for (int q = 0; q < 16; ++q) {                                             \
      const float4 uq = *(const float4*)&lds_u[4 * q];                         \
      const unsigned d0 = MD0[q >> 2][q & 3];                                  \
      const unsigned d1 = MD1[q >> 2][q & 3];                                  \
      p0 += (float)( d0        & 0xffu) * uq.x;                                \
      p0 += (float)((d0 >>  8) & 0xffu) * uq.y;                                \
      p0 += (float)((d0 >> 16) & 0xffu) * uq.z;                                \
      p0 += (float)( d0 >> 24         ) * uq.w;                                \
      p1 += (float)( d1        & 0xffu) * uq.x;                                \
      p1 += (float)((d1 >>  8) & 0xffu) * uq.y;                                \
      p1 += (float)((d1 >> 16) & 0xffu) * uq.z;                                \
      p1 += (float)( d1 >> 24         ) * uq.w;                                \
    }                                                                          \
    float* pw = part + (size_t)((it & 1) * NBATCH + BIDX) * 16384              \
                     + s * 1024 + w * 128;                                     \
    st_agent(pw + lane,      p0);                                              \
    st_agent(pw + 64 + lane, p1);                                              \
  }                                                                            \
  __syncthreads();  /* per-wave vmcnt(0): plane stores visible before flag */  \
  if (tid == 0)                                                                \
    __hip_atomic_store(FLAGB + s * 16, (unsigned)(it + 1),                     \
                       __ATOMIC_RELEASE, __HIP_MEMORY_SCOPE_AGENT);

// consume phase: redundant 16-plane fixed-order sum (R6-proven), f(), restage
#define CONSUME_PHASE(GST, BIDX, FLAGB, DRED)                                  \
  wait_flags(FLAGB, (unsigned)(it + 1), tid, lane, &s_tmo);                    \
  {                                                                            \
    const float* prb = part + (size_t)((it & 1) * NBATCH + BIDX) * 16384;      \
    float r0 = 0.f, r1 = 0.f;                                                  \
    _Pragma("unroll")                                                          \
    for (int q = 0; q < 16; ++q) {                                             \
      union { unsigned long long u; float f[2]; } c;                           \
      c.u = ld_agent64((const unsigned long long*)(prb + q * 1024) + tid);     \
      r0 += c.f[0]; r1 += c.f[1];                                              \
    }                                                                          \
    const float v0 = 1.0f / (r0 * invc2 + EPSI);                               \
    const float v1 = 1.0f / (r1 * invc2 + EPSI);                               \
    GST[i0] = v0; GST[i0 + 1] = v1;                                            \
    if (it == 99 && s == 0) {                                                  \
      float dterm = v0 * r0 + v1 * r1;                                         \
      _Pragma("unroll")                                                        \
      for (int o = 32; o; o >>= 1) dterm += __shfl_xor(dterm, o, 64);          \
      if (lane == 0) DRED[w] = dterm;                                          \
    }                                                                          \
  }                                                                            \
  __syncthreads();

__global__ __launch_bounds__(512) void sinkhorn_kernel(
    const unsigned char* __restrict__ Cq, const unsigned char* __restrict__ CTq,
    float* __restrict__ part, unsigned* __restrict__ flags, float* __restrict__ dist,
    const unsigned* __restrict__ cmax_bits)
{
  const int wg = blockIdx.x;            // 128 WGs
  const int s  = wg & 15;               // slice
  const int p  = wg >> 4;               // batch pair 0..7
  const int b0 = p, b1 = p + 8;
  const int ob = s * 64;
  const int tid = threadIdx.x, lane = tid & 63, w = tid >> 6;

  __shared__ __align__(16) float gst0[1024];
  __shared__ __align__(16) float gst1[1024];
  __shared__ __align__(16) float lds_u[64];
  __shared__ float dred0[8], dred1[8];
  __shared__ int s_tmo;
  if (tid == 0) s_tmo = 0;

  const float cmax  = __uint_as_float(*cmax_bits);
  const float invc2 = 1.0f / (QSCALE * cmax);   // dequant + /cmax folded

  // one-time matrix load for BOTH batches (128 VGPRs):
  // mc*: 8 C-rows (row ob+w*8+q, bytes [16l,16l+16)); md*: 2 CT-rows per lane
  // (C-cols c0=w*128+lane, c0+64), cols ob..ob+63
  uint32x4 mcA[8], mdA0[4], mdA1[4], mcB[8], mdB0[4], mdB1[4];
  {
    const int c0 = w * 128 + lane;
    const unsigned char* cb = Cq  + (size_t)b0 * NPTS * NPTS;
    const unsigned char* tb = CTq + (size_t)b0 * NPTS * NPTS;
    #pragma unroll
    for (int q = 0; q < 8; ++q)
      mcA[q] = *(const uint32x4*)(cb + (size_t)(ob + w * 8 + q) * NPTS + lane * 16);
    #pragma unroll
    for (int j = 0; j < 4; ++j) {
      mdA0[j] = *(const uint32x4*)(tb + (size_t)c0 * NPTS + ob + j * 16);
      mdA1[j] = *(const uint32x4*)(tb + (size_t)(c0 + 64) * NPTS + ob + j * 16);
    }
    const unsigned char* cb2 = Cq  + (size_t)b1 * NPTS * NPTS;
    const unsigned char* tb2 = CTq + (size_t)b1 * NPTS * NPTS;
    #pragma unroll
    for (int q = 0; q < 8; ++q)
      mcB[q] = *(const uint32x4*)(cb2 + (size_t)(ob + w * 8 + q) * NPTS + lane * 16);
    #pragma unroll
    for (int j = 0; j < 4; ++j) {
      mdB0[j] = *(const uint32x4*)(tb2 + (size_t)c0 * NPTS + ob + j * 16);
      mdB1[j] = *(const uint32x4*)(tb2 + (size_t)(c0 + 64) * NPTS + ob + j * 16);
    }
  }

  unsigned* flag0 = flags + b0 * 256;   // (b*16+s)*16 uints: 64B line per producer
  unsigned* flag1 = flags + b1 * 256;

  // v#0 = 1/N replicated (constant; permutation irrelevant)
  gst0[tid] = 1.0f / (float)NPTS; gst0[tid + 512] = 1.0f / (float)NPTS;
  gst1[tid] = 1.0f / (float)NPTS; gst1[tid + 512] = 1.0f / (float)NPTS;
  // permuted gst slot for this thread's 2 values (m = 2*tid, 2*tid+1) -- proven R2/R5/R6
  const int i0 = ((tid >> 1) & 3) * 256 + (tid >> 3) * 4 + (tid & 1) * 2;
  __syncthreads();

  #pragma unroll 1
  for (int it = 0; it < 100; ++it) {
    COMPUTE_PHASE(gst0, mcA, mdA0, mdA1, b0, flag0)
    COMPUTE_PHASE(gst1, mcB, mdB0, mdB1, b1, flag1)
    CONSUME_PHASE(gst0, b0, flag0, dred0)
    CONSUME_PHASE(gst1, b1, flag1, dred1)
  }

  if (s == 0 && tid == 0) {
    float d0s = 0.f, d1s = 0.f;
    #pragma unroll
    for (int ww = 0; ww < 8; ++ww) { d0s += dred0[ww]; d1s += dred1[ww]; }
    st_agent(&dist[b0], d0s * invc2);
    st_agent(&dist[b1], d1s * invc2);
  }
}

__global__ void finalize_kernel(const float* __restrict__ dist, float* __restrict__ out) {
  if (threadIdx.x == 0) {
    float s = 0.f;
    for (int i = 0; i < NBATCH; ++i) s += dist[i];
    out[0] = s * (1.0f / NBATCH);
  }
}

// ---------------- launch ----------------
extern "C" void kernel_launch(void* const* d_in, const int* in_sizes, int n_in,
                              void* d_out, int out_size, void* d_ws, size_t ws_size,
                              hipStream_t stream) {
  (void)in_sizes; (void)n_in; (void)out_size; (void)ws_size;
  const float* x = (const float*)d_in[0];
  const float* y = (const float*)d_in[1];
  float* out = (float*)d_out;
  char* ws = (char*)d_ws;

  unsigned* cmax_bits = (unsigned*)ws;                 // @0
  float*    dist      = (float*)(ws + 8192);           // 16 floats
  unsigned* flags     = (unsigned*)(ws + 16384);       // 16 x 16 x 64B = 16 KB
  const size_t MB = 1u << 20;
  float*    part      = (float*)(ws + 2*MB);           // [2][16][16][1024] f32 = 2 MB
                                                       // (inside xf region; xf dead by then)
  unsigned short* xf = (unsigned short*)(ws + 1*MB);   // 32 MB bf16 (norm/gemm only)
  unsigned short* yf = (unsigned short*)(ws + 33*MB);  // 32 MB bf16 (norm/gemm only)
  unsigned char*  C  = (unsigned char*)(ws + 65*MB);   // 16 MB u8
  unsigned char*  CT = (unsigned char*)(ws + 81*MB);   // 16 MB u8

  hipMemsetAsync(d_ws, 0, 65536, stream);  // cmax / dist / flags

  hipLaunchKernelGGL(norm_kernel, dim3(2 * NBATCH * NPTS), dim3(256), 0, stream, x, y, xf, yf);
  hipLaunchKernelGGL(gemm_cost, dim3(8, 8, NBATCH), dim3(256), 0, stream, xf, yf, C, CT, cmax_bits);
  hipLaunchKernelGGL(sinkhorn_kernel, dim3(128), dim3(512), 0, stream, C, CT, part, flags, dist, cmax_bits);
  hipLaunchKernelGGL(finalize_kernel, dim3(1), dim3(64), 0, stream, dist, out);
}

// Round 9
// 5932.964 us; speedup vs baseline: 1.3170x; 1.3170x over previous
//
#include <hip/hip_runtime.h>

#define NBATCH 16
#define NPTS   1024
#define NDIM   1024
#define EPSI   1e-3f
#define QSCALE 127.5f
#define SPIN_TIMEOUT_TICKS (1ull << 28)   // s_memrealtime ticks; >>1000x any real wait

typedef __attribute__((ext_vector_type(8))) short short8;
typedef __attribute__((ext_vector_type(4))) float f32x4;
typedef __attribute__((ext_vector_type(4))) unsigned uint32x4;

__device__ __forceinline__ unsigned short f2bf(float f) {
  union { float f; unsigned u; } v; v.f = f;
  unsigned r = v.u + 0x7fffu + ((v.u >> 16) & 1u);
  return (unsigned short)(r >> 16);
}

// device-coherent scalar access (per-access sc bits; NO cache-wide fences)
__device__ __forceinline__ void st_agent(float* p, float v) {
  __hip_atomic_store(p, v, __ATOMIC_RELAXED, __HIP_MEMORY_SCOPE_AGENT);
}
__device__ __forceinline__ unsigned long long ld_agent64(const unsigned long long* p) {
  return __hip_atomic_load(p, __ATOMIC_RELAXED, __HIP_MEMORY_SCOPE_AGENT);
}

// ---------------- normalize: fp32 [B,N,D] -> unit rows, bf16 ----------------
__global__ __launch_bounds__(256) void norm_kernel(const float* __restrict__ x,
                                                   const float* __restrict__ y,
                                                   unsigned short* __restrict__ xf,
                                                   unsigned short* __restrict__ yf) {
  int row = blockIdx.x;
  const float* src; unsigned short* dst;
  if (row < NBATCH * NPTS) { src = x; dst = xf; }
  else { row -= NBATCH * NPTS; src = y; dst = yf; }
  src += (size_t)row * NDIM; dst += (size_t)row * NDIM;
  const int t = threadIdx.x;
  float4 val = ((const float4*)src)[t];
  float ss = val.x*val.x + val.y*val.y + val.z*val.z + val.w*val.w;
  #pragma unroll
  for (int o = 32; o; o >>= 1) ss += __shfl_xor(ss, o, 64);
  __shared__ float wsum[4];
  if ((t & 63) == 0) wsum[t >> 6] = ss;
  __syncthreads();
  float tot = wsum[0] + wsum[1] + wsum[2] + wsum[3];
  float inv = 1.0f / fmaxf(sqrtf(tot), 1e-12f);
  ushort4 o4;
  o4.x = f2bf(val.x * inv); o4.y = f2bf(val.y * inv);
  o4.z = f2bf(val.z * inv); o4.w = f2bf(val.w * inv);
  ((ushort4*)dst)[t] = o4;
}

// ------- batched bf16 GEMM: writes BOTH Cq = q8(1 - A B^T) and its transpose -------
#define GLD_LDS16(g, l) __builtin_amdgcn_global_load_lds( \
    (const __attribute__((address_space(1))) unsigned int*)(g), \
    (__attribute__((address_space(3))) unsigned int*)(l), 16, 0, 0)

__device__ __forceinline__ unsigned char q8(float cv) {
  float t = cv * QSCALE + 0.5f;
  t = fminf(fmaxf(t, 0.f), 255.f);
  return (unsigned char)(int)t;
}

__global__ __launch_bounds__(256) void gemm_cost(const unsigned short* __restrict__ A,
                                                 const unsigned short* __restrict__ B,
                                                 unsigned char* __restrict__ Cq,
                                                 unsigned char* __restrict__ CTq,
                                                 unsigned* __restrict__ cmax_bits) {
  const int b = blockIdx.z;
  const int bm = blockIdx.y * 128, bn = blockIdx.x * 128;
  const int t = threadIdx.x, lane = t & 63, wv = t >> 6;
  const int wm = (wv & 1) * 64, wn = (wv >> 1) * 64;
  __shared__ unsigned short As[128 * 32];
  __shared__ unsigned short Bs[128 * 32];
  f32x4 acc[4][4];
  #pragma unroll
  for (int i = 0; i < 4; ++i)
    #pragma unroll
    for (int j = 0; j < 4; ++j) acc[i][j] = (f32x4){0.f, 0.f, 0.f, 0.f};

  const unsigned short* gA = A + (size_t)b*NPTS*NDIM + (size_t)(bm + (t >> 2))*NDIM + (t & 3)*8;
  const unsigned short* gB = B + (size_t)b*NPTS*NDIM + (size_t)(bn + (t >> 2))*NDIM + (t & 3)*8;
  const int ar = lane & 15, ak = (lane >> 4) * 8;

  for (int k0 = 0; k0 < NDIM; k0 += 32) {
    GLD_LDS16(gA + k0,             As + t*8);
    GLD_LDS16(gA + 64*NDIM + k0,   As + 2048 + t*8);
    GLD_LDS16(gB + k0,             Bs + t*8);
    GLD_LDS16(gB + 64*NDIM + k0,   Bs + 2048 + t*8);
    __syncthreads();
    short8 af[4], bq[4];
    #pragma unroll
    for (int i = 0; i < 4; ++i) af[i] = *(const short8*)(As + (wm + i*16 + ar)*32 + ak);
    #pragma unroll
    for (int j = 0; j < 4; ++j) bq[j] = *(const short8*)(Bs + (wn + j*16 + ar)*32 + ak);
    #pragma unroll
    for (int i = 0; i < 4; ++i)
      #pragma unroll
      for (int j = 0; j < 4; ++j)
        acc[i][j] = __builtin_amdgcn_mfma_f32_16x16x32_bf16(af[i], bq[j], acc[i][j], 0, 0, 0);
    __syncthreads();
  }

  float mx = 0.f;
  const int cr = (lane >> 4) * 4, cc = lane & 15;
  unsigned char* Cb = Cq  + (size_t)b * NPTS * NPTS;
  unsigned char* Tb = CTq + (size_t)b * NPTS * NPTS;
  #pragma unroll
  for (int i = 0; i < 4; ++i) {
    #pragma unroll
    for (int j = 0; j < 4; ++j) {
      const int row0 = bm + wm + i*16 + cr;
      const int col  = bn + wn + j*16 + cc;
      #pragma unroll
      for (int r = 0; r < 4; ++r) {
        float cv = 1.0f - acc[i][j][r];
        mx = fmaxf(mx, cv);
        unsigned char qv = q8(cv);
        Cb[(size_t)(row0 + r) * NPTS + col] = qv;
        Tb[(size_t)col * NPTS + row0 + r]   = qv;
      }
    }
  }
  #pragma unroll
  for (int o = 32; o; o >>= 1) mx = fmaxf(mx, __shfl_xor(mx, o, 64));
  if (lane == 0) atomicMax(cmax_bits, __float_as_uint(mx));
}

// ---- persistent Sinkhorn: dual-batch pipeline + counter barriers + XCD locality ----
// 128 WGs x 512 thr. Decode p = wg&7, s = wg>>3: with round-robin dispatch all 16
// slices of pair p land on XCD p, so each batch's barrier line + partial planes stay
// in ONE L2 (intra-XCD RMW/poll; correctness-neutral if mapping differs).
// WG (p,s) runs slice s of batches b0=p, b1=p+8:
//   compute0 -> arrive0 -> compute1 -> arrive1 -> wait0 -> consume0 -> wait1 -> consume1
// Arrive = single fetch_add (R6-proven); wait = ONE-line poll w/ s_sleep every round
// (R8 lesson: 16-line polling = 4.4GB of HBM poll traffic = congestion collapse).
// compute1 sits between arrive0 and wait0 -> hides store->visibility latency.
// Plane parity WAR safe: write(it+1) happens after wait(bar>=16(it+1)) => all WGs
// finished compute(it) => all finished consume(it-1) (program order) => no reader
// of parity-(it+1) buffer remains. Distance at it==99 (s==0 WG), invc2 at the end.

__device__ __forceinline__ float dot16(uint32x4 q, f32x4 g0, f32x4 g1, f32x4 g2, f32x4 g3) {
  float a = 0.f;
  a += (float)( q.x        & 0xffu) * g0.x;   // v_cvt_f32_ubyte0
  a += (float)((q.x >>  8) & 0xffu) * g0.y;
  a += (float)((q.x >> 16) & 0xffu) * g0.z;
  a += (float)( q.x >> 24         ) * g0.w;
  a += (float)( q.y        & 0xffu) * g1.x;
  a += (float)((q.y >>  8) & 0xffu) * g1.y;
  a += (float)((q.y >> 16) & 0xffu) * g1.z;
  a += (float)( q.y >> 24         ) * g1.w;
  a += (float)( q.z        & 0xffu) * g2.x;
  a += (float)((q.z >>  8) & 0xffu) * g2.y;
  a += (float)((q.z >> 16) & 0xffu) * g2.z;
  a += (float)( q.z >> 24         ) * g2.w;
  a += (float)( q.w        & 0xffu) * g3.x;
  a += (float)((q.w >>  8) & 0xffu) * g3.y;
  a += (float)((q.w >> 16) & 0xffu) * g3.z;
  a += (float)( q.w >> 24         ) * g3.w;
  return a;
}

// single-line counter poll (R0/R6-proven cadence: sleep every round, sticky timeout)
__device__ __forceinline__ void wait_count(const unsigned* barb, unsigned target,
                                           int tid, int* s_tmo) {
  if (tid == 0) {
    if (!*s_tmo) {
      int polls = 0; unsigned long long t0 = 0;
      while (__hip_atomic_load(barb, __ATOMIC_RELAXED, __HIP_MEMORY_SCOPE_AGENT) < target) {
        __builtin_amdgcn_s_sleep(1);
        if ((++polls & 63) == 0) {
          if (!t0) t0 = __builtin_amdgcn_s_memrealtime();
          else if (__builtin_amdgcn_s_memrealtime() - t0 > SPIN_TIMEOUT_TICKS) { *s_tmo = 1; break; }
        }
      }
    }
    asm volatile("" ::: "memory");
  }
  __syncthreads();
}

// compute phase: u for 8 rows -> LDS hop -> partials for all m -> plane store -> arrive
#define COMPUTE_PHASE(GST, MC, MD0, MD1, BIDX, BARB)                           \
  {                                                                            \
    const f32x4 g0 = *(const f32x4*)&GST[      lane * 4];                      \
    const f32x4 g1 = *(const f32x4*)&GST[256 + lane * 4];                      \
    const f32x4 g2 = *(const f32x4*)&GST[512 + lane * 4];                      \
    const f32x4 g3 = *(const f32x4*)&GST[768 + lane * 4];                      \
    float myu = 0.f;                                                           \
    _Pragma("unroll")                                                          \
    for (int q = 0; q < 8; ++q) {                                              \
      float acc = dot16(MC[q], g0, g1, g2, g3);                                \
      _Pragma("unroll")                                                        \
      for (int o = 32; o; o >>= 1) acc += __shfl_xor(acc, o, 64);              \
      const float val = 1.0f / (acc * invc2 + EPSI);                           \
      myu = (lane == q) ? val : myu;                                           \
    }                                                                          \
    if (lane < 8) lds_u[w * 8 + lane] = myu;                                   \
  }                                                                            \
  __syncthreads();                                                             \
  {                                                                            \
    float p0 = 0.f, p1 = 0.f;                                                  \
    _Pragma("unroll")                                                          \
    for (int q = 0; q < 16; ++q) {                                             \
      const float4 uq = *(const float4*)&lds_u[4 * q];                         \
      const unsigned d0 = MD0[q >> 2][q & 3];                                  \
      const unsigned d1 = MD1[q >> 2][q & 3];                                  \
      p0 += (float)( d0        & 0xffu) * uq.x;                                \
      p0 += (float)((d0 >>  8) & 0xffu) * uq.y;                                \
      p0 += (float)((d0 >> 16) & 0xffu) * uq.z;                                \
      p0 += (float)( d0 >> 24         ) * uq.w;                                \
      p1 += (float)( d1        & 0xffu) * uq.x;                                \
      p1 += (float)((d1 >>  8) & 0xffu) * uq.y;                                \
      p1 += (float)((d1 >> 16) & 0xffu) * uq.z;                                \
      p1 += (float)( d1 >> 24         ) * uq.w;                                \
    }                                                                          \
    float* pw = part + (size_t)((it & 1) * NBATCH + BIDX) * 16384              \
                     + s * 1024 + w * 128;                                     \
    st_agent(pw + lane,      p0);                                              \
    st_agent(pw + 64 + lane, p1);                                              \
  }                                                                            \
  __syncthreads();  /* per-wave vmcnt(0): plane stores visible before arrive */\
  if (tid == 0)                                                                \
    __hip_atomic_fetch_add(BARB, 1u, __ATOMIC_RELEASE, __HIP_MEMORY_SCOPE_AGENT);

// consume phase: redundant 16-plane fixed-order sum (R6-proven), f(), restage
#define CONSUME_PHASE(GST, BIDX, BARB, DRED)                                   \
  wait_count(BARB, 16u * (unsigned)(it + 1), tid, &s_tmo);                     \
  {                                                                            \
    const float* prb = part + (size_t)((it & 1) * NBATCH + BIDX) * 16384;      \
    float r0 = 0.f, r1 = 0.f;                                                  \
    _Pragma("unroll")                                                          \
    for (int q = 0; q < 16; ++q) {                                             \
      union { unsigned long long u; float f[2]; } c;                           \
      c.u = ld_agent64((const unsigned long long*)(prb + q * 1024) + tid);     \
      r0 += c.f[0]; r1 += c.f[1];                                              \
    }                                                                          \
    const float v0 = 1.0f / (r0 * invc2 + EPSI);                               \
    const float v1 = 1.0f / (r1 * invc2 + EPSI);                               \
    GST[i0] = v0; GST[i0 + 1] = v1;                                            \
    if (it == 99 && s == 0) {                                                  \
      float dterm = v0 * r0 + v1 * r1;                                         \
      _Pragma("unroll")                                                        \
      for (int o = 32; o; o >>= 1) dterm += __shfl_xor(dterm, o, 64);          \
      if (lane == 0) DRED[w] = dterm;                                          \
    }                                                                          \
  }                                                                            \
  __syncthreads();

__global__ __launch_bounds__(512) void sinkhorn_kernel(
    const unsigned char* __restrict__ Cq, const unsigned char* __restrict__ CTq,
    float* __restrict__ part, unsigned* __restrict__ bar, float* __restrict__ dist,
    const unsigned* __restrict__ cmax_bits)
{
  const int wg = blockIdx.x;            // 128 WGs
  const int p  = wg & 7;                // pair id == XCD (round-robin dispatch)
  const int s  = wg >> 3;               // slice 0..15 (all slices of pair p on XCD p)
  const int b0 = p, b1 = p + 8;
  const int ob = s * 64;
  const int tid = threadIdx.x, lane = tid & 63, w = tid >> 6;

  __shared__ __align__(16) float gst0[1024];
  __shared__ __align__(16) float gst1[1024];
  __shared__ __align__(16) float lds_u[64];
  __shared__ float dred0[8], dred1[8];
  __shared__ int s_tmo;
  if (tid == 0) s_tmo = 0;

  const float cmax  = __uint_as_float(*cmax_bits);
  const float invc2 = 1.0f / (QSCALE * cmax);   // dequant + /cmax folded

  // one-time matrix load for BOTH batches (128 VGPRs):
  // mc*: 8 C-rows (row ob+w*8+q, bytes [16l,16l+16)); md*: 2 CT-rows per lane
  // (C-cols c0=w*128+lane, c0+64), cols ob..ob+63
  uint32x4 mcA[8], mdA0[4], mdA1[4], mcB[8], mdB0[4], mdB1[4];
  {
    const int c0 = w * 128 + lane;
    const unsigned char* cb = Cq  + (size_t)b0 * NPTS * NPTS;
    const unsigned char* tb = CTq + (size_t)b0 * NPTS * NPTS;
    #pragma unroll
    for (int q = 0; q < 8; ++q)
      mcA[q] = *(const uint32x4*)(cb + (size_t)(ob + w * 8 + q) * NPTS + lane * 16);
    #pragma unroll
    for (int j = 0; j < 4; ++j) {
      mdA0[j] = *(const uint32x4*)(tb + (size_t)c0 * NPTS + ob + j * 16);
      mdA1[j] = *(const uint32x4*)(tb + (size_t)(c0 + 64) * NPTS + ob + j * 16);
    }
    const unsigned char* cb2 = Cq  + (size_t)b1 * NPTS * NPTS;
    const unsigned char* tb2 = CTq + (size_t)b1 * NPTS * NPTS;
    #pragma unroll
    for (int q = 0; q < 8; ++q)
      mcB[q] = *(const uint32x4*)(cb2 + (size_t)(ob + w * 8 + q) * NPTS + lane * 16);
    #pragma unroll
    for (int j = 0; j < 4; ++j) {
      mdB0[j] = *(const uint32x4*)(tb2 + (size_t)c0 * NPTS + ob + j * 16);
      mdB1[j] = *(const uint32x4*)(tb2 + (size_t)(c0 + 64) * NPTS + ob + j * 16);
    }
  }

  unsigned* bar0 = bar + b0 * 64;      // 256B-spaced counter lines, one per batch
  unsigned* bar1 = bar + b1 * 64;

  // v#0 = 1/N replicated (constant; permutation irrelevant)
  gst0[tid] = 1.0f / (float)NPTS; gst0[tid + 512] = 1.0f / (float)NPTS;
  gst1[tid] = 1.0f / (float)NPTS; gst1[tid + 512] = 1.0f / (float)NPTS;
  // permuted gst slot for this thread's 2 values (m = 2*tid, 2*tid+1) -- proven R2/R5/R6
  const int i0 = ((tid >> 1) & 3) * 256 + (tid >> 3) * 4 + (tid & 1) * 2;
  __syncthreads();

  #pragma unroll 1
  for (int it = 0; it < 100; ++it) {
    COMPUTE_PHASE(gst0, mcA, mdA0, mdA1, b0, bar0)
    COMPUTE_PHASE(gst1, mcB, mdB0, mdB1, b1, bar1)
    CONSUME_PHASE(gst0, b0, bar0, dred0)
    CONSUME_PHASE(gst1, b1, bar1, dred1)
  }

  if (s == 0 && tid == 0) {
    float d0s = 0.f, d1s = 0.f;
    #pragma unroll
    for (int ww = 0; ww < 8; ++ww) { d0s += dred0[ww]; d1s += dred1[ww]; }
    st_agent(&dist[b0], d0s * invc2);
    st_agent(&dist[b1], d1s * invc2);
  }
}

__global__ void finalize_kernel(const float* __restrict__ dist, float* __restrict__ out) {
  if (threadIdx.x == 0) {
    float s = 0.f;
    for (int i = 0; i < NBATCH; ++i) s += dist[i];
    out[0] = s * (1.0f / NBATCH);
  }
}

// ---------------- launch ----------------
extern "C" void kernel_launch(void* const* d_in, const int* in_sizes, int n_in,
                              void* d_out, int out_size, void* d_ws, size_t ws_size,
                              hipStream_t stream) {
  (void)in_sizes; (void)n_in; (void)out_size; (void)ws_size;
  const float* x = (const float*)d_in[0];
  const float* y = (const float*)d_in[1];
  float* out = (float*)d_out;
  char* ws = (char*)d_ws;

  unsigned* cmax_bits = (unsigned*)ws;                 // @0
  unsigned* bar       = (unsigned*)(ws + 4096);        // 16 x 256B counter lines
  float*    dist      = (float*)(ws + 8192);           // 16 floats
  const size_t MB = 1u << 20;
  float*    part      = (float*)(ws + 2*MB);           // [2][16][16][1024] f32 = 2 MB
                                                       // (inside xf region; xf dead by then)
  unsigned short* xf = (unsigned short*)(ws + 1*MB);   // 32 MB bf16 (norm/gemm only)
  unsigned short* yf = (unsigned short*)(ws + 33*MB);  // 32 MB bf16 (norm/gemm only)
  unsigned char*  C  = (unsigned char*)(ws + 65*MB);   // 16 MB u8
  unsigned char*  CT = (unsigned char*)(ws + 81*MB);   // 16 MB u8

  hipMemsetAsync(d_ws, 0, 65536, stream);  // cmax / barriers / dist

  hipLaunchKernelGGL(norm_kernel, dim3(2 * NBATCH * NPTS), dim3(256), 0, stream, x, y, xf, yf);
  hipLaunchKernelGGL(gemm_cost, dim3(8, 8, NBATCH), dim3(256), 0, stream, xf, yf, C, CT, cmax_bits);
  hipLaunchKernelGGL(sinkhorn_kernel, dim3(128), dim3(512), 0, stream, C, CT, part, bar, dist, cmax_bits);
  hipLaunchKernelGGL(finalize_kernel, dim3(1), dim3(64), 0, stream, dist, out);
}

// Round 10
// 1220.662 us; speedup vs baseline: 6.4010x; 4.8604x over previous
//
#include <hip/hip_runtime.h>

#define NBATCH 16
#define NPTS   1024
#define NDIM   1024
#define EPSI   1e-3f
#define QSCALE 127.5f
#define SPIN_TIMEOUT_TICKS (1ull << 28)   // s_memrealtime ticks; >>1000x any real wait

typedef __attribute__((ext_vector_type(8))) short short8;
typedef __attribute__((ext_vector_type(4))) float f32x4;
typedef __attribute__((ext_vector_type(4))) unsigned uint32x4;

__device__ __forceinline__ unsigned short f2bf(float f) {
  union { float f; unsigned u; } v; v.f = f;
  unsigned r = v.u + 0x7fffu + ((v.u >> 16) & 1u);
  return (unsigned short)(r >> 16);
}

// device-coherent scalar access (per-access sc bits; NO cache-wide fences)
__device__ __forceinline__ float ld_agent(const float* p) {
  return __hip_atomic_load(p, __ATOMIC_RELAXED, __HIP_MEMORY_SCOPE_AGENT);
}
__device__ __forceinline__ void st_agent(float* p, float v) {
  __hip_atomic_store(p, v, __ATOMIC_RELAXED, __HIP_MEMORY_SCOPE_AGENT);
}
__device__ __forceinline__ unsigned long long ld_agent64(const unsigned long long* p) {
  return __hip_atomic_load(p, __ATOMIC_RELAXED, __HIP_MEMORY_SCOPE_AGENT);
}

// ---------------- normalize: fp32 [B,N,D] -> unit rows, bf16 ----------------
__global__ __launch_bounds__(256) void norm_kernel(const float* __restrict__ x,
                                                   const float* __restrict__ y,
                                                   unsigned short* __restrict__ xf,
                                                   unsigned short* __restrict__ yf) {
  int row = blockIdx.x;
  const float* src; unsigned short* dst;
  if (row < NBATCH * NPTS) { src = x; dst = xf; }
  else { row -= NBATCH * NPTS; src = y; dst = yf; }
  src += (size_t)row * NDIM; dst += (size_t)row * NDIM;
  const int t = threadIdx.x;
  float4 val = ((const float4*)src)[t];
  float ss = val.x*val.x + val.y*val.y + val.z*val.z + val.w*val.w;
  #pragma unroll
  for (int o = 32; o; o >>= 1) ss += __shfl_xor(ss, o, 64);
  __shared__ float wsum[4];
  if ((t & 63) == 0) wsum[t >> 6] = ss;
  __syncthreads();
  float tot = wsum[0] + wsum[1] + wsum[2] + wsum[3];
  float inv = 1.0f / fmaxf(sqrtf(tot), 1e-12f);
  ushort4 o4;
  o4.x = f2bf(val.x * inv); o4.y = f2bf(val.y * inv);
  o4.z = f2bf(val.z * inv); o4.w = f2bf(val.w * inv);
  ((ushort4*)dst)[t] = o4;
}

// ------- batched bf16 GEMM: writes BOTH Cq = q8(1 - A B^T) and its transpose -------
#define GLD_LDS16(g, l) __builtin_amdgcn_global_load_lds( \
    (const __attribute__((address_space(1))) unsigned int*)(g), \
    (__attribute__((address_space(3))) unsigned int*)(l), 16, 0, 0)

__device__ __forceinline__ unsigned char q8(float cv) {
  float t = cv * QSCALE + 0.5f;
  t = fminf(fmaxf(t, 0.f), 255.f);
  return (unsigned char)(int)t;
}

__global__ __launch_bounds__(256) void gemm_cost(const unsigned short* __restrict__ A,
                                                 const unsigned short* __restrict__ B,
                                                 unsigned char* __restrict__ Cq,
                                                 unsigned char* __restrict__ CTq,
                                                 unsigned* __restrict__ cmax_bits) {
  const int b = blockIdx.z;
  const int bm = blockIdx.y * 128, bn = blockIdx.x * 128;
  const int t = threadIdx.x, lane = t & 63, wv = t >> 6;
  const int wm = (wv & 1) * 64, wn = (wv >> 1) * 64;
  __shared__ unsigned short As[128 * 32];
  __shared__ unsigned short Bs[128 * 32];
  f32x4 acc[4][4];
  #pragma unroll
  for (int i = 0; i < 4; ++i)
    #pragma unroll
    for (int j = 0; j < 4; ++j) acc[i][j] = (f32x4){0.f, 0.f, 0.f, 0.f};

  const unsigned short* gA = A + (size_t)b*NPTS*NDIM + (size_t)(bm + (t >> 2))*NDIM + (t & 3)*8;
  const unsigned short* gB = B + (size_t)b*NPTS*NDIM + (size_t)(bn + (t >> 2))*NDIM + (t & 3)*8;
  const int ar = lane & 15, ak = (lane >> 4) * 8;

  for (int k0 = 0; k0 < NDIM; k0 += 32) {
    GLD_LDS16(gA + k0,             As + t*8);
    GLD_LDS16(gA + 64*NDIM + k0,   As + 2048 + t*8);
    GLD_LDS16(gB + k0,             Bs + t*8);
    GLD_LDS16(gB + 64*NDIM + k0,   Bs + 2048 + t*8);
    __syncthreads();
    short8 af[4], bq[4];
    #pragma unroll
    for (int i = 0; i < 4; ++i) af[i] = *(const short8*)(As + (wm + i*16 + ar)*32 + ak);
    #pragma unroll
    for (int j = 0; j < 4; ++j) bq[j] = *(const short8*)(Bs + (wn + j*16 + ar)*32 + ak);
    #pragma unroll
    for (int i = 0; i < 4; ++i)
      #pragma unroll
      for (int j = 0; j < 4; ++j)
        acc[i][j] = __builtin_amdgcn_mfma_f32_16x16x32_bf16(af[i], bq[j], acc[i][j], 0, 0, 0);
    __syncthreads();
  }

  float mx = 0.f;
  const int cr = (lane >> 4) * 4, cc = lane & 15;
  unsigned char* Cb = Cq  + (size_t)b * NPTS * NPTS;
  unsigned char* Tb = CTq + (size_t)b * NPTS * NPTS;
  #pragma unroll
  for (int i = 0; i < 4; ++i) {
    #pragma unroll
    for (int j = 0; j < 4; ++j) {
      const int row0 = bm + wm + i*16 + cr;
      const int col  = bn + wn + j*16 + cc;
      #pragma unroll
      for (int r = 0; r < 4; ++r) {
        float cv = 1.0f - acc[i][j][r];
        mx = fmaxf(mx, cv);
        unsigned char qv = q8(cv);
        Cb[(size_t)(row0 + r) * NPTS + col] = qv;
        Tb[(size_t)col * NPTS + row0 + r]   = qv;
      }
    }
  }
  #pragma unroll
  for (int o = 32; o; o >>= 1) mx = fmaxf(mx, __shfl_xor(mx, o, 64));
  if (lane == 0) atomicMax(cmax_bits, __float_as_uint(mx));
}

// -------- persistent Sinkhorn: R6 structure + single-line 16-slot flag sync --------
// IDENTICAL to R6 (256 WGs x 512 thr, b=wg&15 decode [load-bearing: keeps each
// batch's producers/consumers/planes on ONE XCD], one sync/iter, fused U+V partials,
// redundant 16-plane fixed-order consume) except the sync primitive:
//   R6 arrive = 16 serialized fetch_add RMWs on one line (~5.1us of the 10.7us iter,
//   per the R6/R7 decomposition). Here: producer s release-STORES it+1 into slot s of
//   a single 64B line (no RMW, no ownership serialization); waiter polls lanes 0..15
//   reading the 16 slots of that ONE line = one transaction per poll round (R8's
//   fatal flaw was 16 SEPARATE lines = 16 transactions/poll = 4.4GB HBM storm).
// Sleep-every-poll + sticky timeout (proven R0/R6). vmcnt drain before flag store,
// parity WAR causality, monotone tags: all unchanged from R6.

__device__ __forceinline__ float dot16(uint32x4 q, f32x4 g0, f32x4 g1, f32x4 g2, f32x4 g3) {
  float a = 0.f;
  a += (float)( q.x        & 0xffu) * g0.x;   // v_cvt_f32_ubyte0
  a += (float)((q.x >>  8) & 0xffu) * g0.y;
  a += (float)((q.x >> 16) & 0xffu) * g0.z;
  a += (float)( q.x >> 24         ) * g0.w;
  a += (float)( q.y        & 0xffu) * g1.x;
  a += (float)((q.y >>  8) & 0xffu) * g1.y;
  a += (float)((q.y >> 16) & 0xffu) * g1.z;
  a += (float)( q.y >> 24         ) * g1.w;
  a += (float)( q.z        & 0xffu) * g2.x;
  a += (float)((q.z >>  8) & 0xffu) * g2.y;
  a += (float)((q.z >> 16) & 0xffu) * g2.z;
  a += (float)( q.z >> 24         ) * g2.w;
  a += (float)( q.w        & 0xffu) * g3.x;
  a += (float)((q.w >>  8) & 0xffu) * g3.y;
  a += (float)((q.w >> 16) & 0xffu) * g3.z;
  a += (float)( q.w >> 24         ) * g3.w;
  return a;
}

#define LOAD_G(buf)                                          \
  const f32x4 g0 = *(const f32x4*)&buf[      lane * 4];      \
  const f32x4 g1 = *(const f32x4*)&buf[256 + lane * 4];      \
  const f32x4 g2 = *(const f32x4*)&buf[512 + lane * 4];      \
  const f32x4 g3 = *(const f32x4*)&buf[768 + lane * 4];

// arrive+wait: slot store (no RMW) then whole-wave poll of the single 64B flag line
__device__ __forceinline__ void flag_sync(unsigned* flagb, int s, unsigned tag,
                                          int tid, int lane, int* s_tmo) {
  // caller did __syncthreads() => every wave's plane stores drained (vmcnt 0)
  if (tid == 0)
    __hip_atomic_store(flagb + s, tag, __ATOMIC_RELEASE, __HIP_MEMORY_SCOPE_AGENT);
  if (tid < 64) {
    if (!*s_tmo) {
      int polls = 0; unsigned long long t0 = 0;
      for (;;) {
        unsigned val = tag;
        if (lane < 16)
          val = __hip_atomic_load(flagb + lane, __ATOMIC_RELAXED, __HIP_MEMORY_SCOPE_AGENT);
        if (__all(val >= tag)) break;
        __builtin_amdgcn_s_sleep(1);
        if ((++polls & 63) == 0) {
          if (!t0) t0 = __builtin_amdgcn_s_memrealtime();
          else if (__builtin_amdgcn_s_memrealtime() - t0 > SPIN_TIMEOUT_TICKS) { *s_tmo = 1; break; }
        }
      }
    }
    asm volatile("" ::: "memory");
  }
  __syncthreads();
}

__global__ __launch_bounds__(512) void sinkhorn_kernel(
    const unsigned char* __restrict__ Cq, const unsigned char* __restrict__ CTq,
    float* __restrict__ part, unsigned* __restrict__ flags, float* __restrict__ dist,
    const unsigned* __restrict__ cmax_bits)
{
  const int wg = blockIdx.x;
  const int b = wg & (NBATCH - 1);      // R6 decode -- load-bearing for XCD locality
  const int s = wg >> 4;
  const int ob = s * 64;
  const int tid = threadIdx.x, lane = tid & 63, w = tid >> 6;

  __shared__ __align__(16) float gst[1024];
  __shared__ __align__(16) float lds_u[64];
  __shared__ float dred[8];
  __shared__ int s_tmo;
  if (tid == 0) s_tmo = 0;

  const float cmax  = __uint_as_float(*cmax_bits);
  const float invc2 = 1.0f / (QSCALE * cmax);   // dequant + /cmax folded

  // one-time matrix load: mc = 8 C-rows (row ob+w*8+p, bytes [16l,16l+16));
  // md0/md1 = 2 CT-rows per lane (C-cols c0=w*128+lane, c0+64), cols ob..ob+63
  uint32x4 mc[8];
  {
    const unsigned char* cb = Cq + (size_t)b * NPTS * NPTS;
    #pragma unroll
    for (int p = 0; p < 8; ++p)
      mc[p] = *(const uint32x4*)(cb + (size_t)(ob + w * 8 + p) * NPTS + lane * 16);
  }
  uint32x4 md0[4], md1[4];
  {
    const unsigned char* tb = CTq + (size_t)b * NPTS * NPTS;
    const int c0 = w * 128 + lane;
    #pragma unroll
    for (int j = 0; j < 4; ++j) {
      md0[j] = *(const uint32x4*)(tb + (size_t)c0 * NPTS + ob + j * 16);
      md1[j] = *(const uint32x4*)(tb + (size_t)(c0 + 64) * NPTS + ob + j * 16);
    }
  }

  unsigned* flagb = flags + b * 64;     // one 64B flag line per batch (256B spacing)

  // v#0 = 1/N replicated (constant; permutation irrelevant)
  gst[tid]       = 1.0f / (float)NPTS;
  gst[tid + 512] = 1.0f / (float)NPTS;
  // permuted gst slot for this thread's 2 values (m = 2*tid, 2*tid+1) -- proven R2/R5/R6
  const int i0 = ((tid >> 1) & 3) * 256 + (tid >> 3) * 4 + (tid & 1) * 2;
  __syncthreads();

  #pragma unroll 1
  for (int it = 0; it < 100; ++it) {
    // ---- u_n = f(C[n,:].v#it) for our 8 rows (per wave)
    LOAD_G(gst);
    float myu = 0.f;
    #pragma unroll
    for (int p = 0; p < 8; ++p) {
      float acc = dot16(mc[p], g0, g1, g2, g3);
      #pragma unroll
      for (int o = 32; o; o >>= 1) acc += __shfl_xor(acc, o, 64);
      const float val = 1.0f / (acc * invc2 + EPSI);
      myu = (lane == p) ? val : myu;
    }
    if (lane < 8) lds_u[w * 8 + lane] = myu;
    __syncthreads();

    // ---- partial_m = sum_{n in R} CT[m,n] u_n for this lane's 2 columns
    float p0 = 0.f, p1 = 0.f;
    #pragma unroll
    for (int q = 0; q < 16; ++q) {
      const float4 uq = *(const float4*)&lds_u[4 * q];   // broadcast read
      const unsigned d0 = md0[q >> 2][q & 3];
      const unsigned d1 = md1[q >> 2][q & 3];
      p0 += (float)( d0        & 0xffu) * uq.x;
      p0 += (float)((d0 >>  8) & 0xffu) * uq.y;
      p0 += (float)((d0 >> 16) & 0xffu) * uq.z;
      p0 += (float)( d0 >> 24         ) * uq.w;
      p1 += (float)( d1        & 0xffu) * uq.x;
      p1 += (float)((d1 >>  8) & 0xffu) * uq.y;
      p1 += (float)((d1 >> 16) & 0xffu) * uq.z;
      p1 += (float)( d1 >> 24         ) * uq.w;
    }
    float* pw = part + (size_t)((it & 1) * NBATCH + b) * 16384 + s * 1024 + w * 128;
    st_agent(pw + lane,      p0);
    st_agent(pw + 64 + lane, p1);

    // ---- ONE sync point: slot store + single-line poll (vmcnt drained by syncthreads)
    __syncthreads();
    flag_sync(flagb, s, (unsigned)(it + 1), tid, lane, &s_tmo);

    // ---- consume: sum 16 planes (fixed order), f(), restage v#(it+1)
    const float* prb = part + (size_t)((it & 1) * NBATCH + b) * 16384;
    float r0 = 0.f, r1 = 0.f;
    #pragma unroll
    for (int q = 0; q < 16; ++q) {
      union { unsigned long long u; float f[2]; } c;
      c.u = ld_agent64((const unsigned long long*)(prb + q * 1024) + tid);
      r0 += c.f[0]; r1 += c.f[1];
    }
    const float v0 = 1.0f / (r0 * invc2 + EPSI);
    const float v1 = 1.0f / (r1 * invc2 + EPSI);
    gst[i0]     = v0;
    gst[i0 + 1] = v1;

    if (it == 99 && s == 0) {   // distance: sum_m f(raw_m)*raw_m*invc2 == u^T C~ v
      float dterm = v0 * r0 + v1 * r1;
      #pragma unroll
      for (int o = 32; o; o >>= 1) dterm += __shfl_xor(dterm, o, 64);
      if (lane == 0) dred[w] = dterm;
    }
    __syncthreads();
  }

  if (s == 0 && tid == 0) {
    float d = 0.f;
    #pragma unroll
    for (int ww = 0; ww < 8; ++ww) d += dred[ww];
    st_agent(&dist[b], d * invc2);
  }
}

__global__ void finalize_kernel(const float* __restrict__ dist, float* __restrict__ out) {
  if (threadIdx.x == 0) {
    float s = 0.f;
    for (int i = 0; i < NBATCH; ++i) s += dist[i];
    out[0] = s * (1.0f / NBATCH);
  }
}

// ---------------- launch ----------------
extern "C" void kernel_launch(void* const* d_in, const int* in_sizes, int n_in,
                              void* d_out, int out_size, void* d_ws, size_t ws_size,
                              hipStream_t stream) {
  (void)in_sizes; (void)n_in; (void)out_size; (void)ws_size;
  const float* x = (const float*)d_in[0];
  const float* y = (const float*)d_in[1];
  float* out = (float*)d_out;
  char* ws = (char*)d_ws;

  unsigned* cmax_bits = (unsigned*)ws;                 // @0
  unsigned* flags     = (unsigned*)(ws + 4096);        // 16 batches x 64B flag line (256B apart)
  float*    dist      = (float*)(ws + 8192);           // 16 floats
  const size_t MB = 1u << 20;
  float*    part      = (float*)(ws + 2*MB);           // [2][16][16][1024] f32 = 2 MB
                                                       // (inside xf region; xf dead by then)
  unsigned short* xf = (unsigned short*)(ws + 1*MB);   // 32 MB bf16 (norm/gemm only)
  unsigned short* yf = (unsigned short*)(ws + 33*MB);  // 32 MB bf16 (norm/gemm only)
  unsigned char*  C  = (unsigned char*)(ws + 65*MB);   // 16 MB u8
  unsigned char*  CT = (unsigned char*)(ws + 81*MB);   // 16 MB u8

  hipMemsetAsync(d_ws, 0, 65536, stream);  // cmax / flags / dist

  hipLaunchKernelGGL(norm_kernel, dim3(2 * NBATCH * NPTS), dim3(256), 0, stream, x, y, xf, yf);
  hipLaunchKernelGGL(gemm_cost, dim3(8, 8, NBATCH), dim3(256), 0, stream, xf, yf, C, CT, cmax_bits);
  hipLaunchKernelGGL(sinkhorn_kernel, dim3(256), dim3(512), 0, stream, C, CT, part, flags, dist, cmax_bits);
  hipLaunchKernelGGL(finalize_kernel, dim3(1), dim3(64), 0, stream, dist, out);
}